// Round 1
// baseline (499.434 us; speedup 1.0000x reference)
//
#include <hip/hip_runtime.h>

#define NFEAT 64

// ---------------------------------------------------------------------------
// GCN norm aggregation:
//   deg[i]  = 1 (self loop) + #edges with row==i
//   dinv[i] = rsqrt(deg[i])                     (deg >= 1 always)
//   out[c*64+f] = dinv[c]^2 * x[c*64+f]                  (self-loop term)
//               + sum_{e: col[e]==c} dinv[row_e]*dinv[c] * x[row_e*64+f]
// ---------------------------------------------------------------------------

__global__ void k_init_deg(int* __restrict__ deg, int n) {
    int i = blockIdx.x * blockDim.x + threadIdx.x;
    if (i < n) deg[i] = 1;  // self loop contributes 1 to degree
}

__global__ void k_count(const int* __restrict__ rows, int* __restrict__ deg, int E) {
    int e = blockIdx.x * blockDim.x + threadIdx.x;
    if (e < E) atomicAdd(&deg[rows[e]], 1);
}

__global__ void k_dinv(const int* __restrict__ deg, float* __restrict__ dinv, int n) {
    int i = blockIdx.x * blockDim.x + threadIdx.x;
    if (i < n) dinv[i] = rsqrtf((float)deg[i]);
}

// Self-loop term doubles as d_out initialization (harness poisons d_out 0xAA).
__global__ void k_self(const float* __restrict__ x, const float* __restrict__ dinv,
                       float* __restrict__ out, long long total) {
    long long idx = (long long)blockIdx.x * blockDim.x + threadIdx.x;
    if (idx < total) {
        int node = (int)(idx >> 6);  // NFEAT = 64
        float d = dinv[node];
        out[idx] = d * d * x[idx];
    }
}

// One wave (64 lanes) per edge: lane f handles feature f. x read and atomic
// destination are 256B-contiguous -> fully coalesced.
__global__ void k_scatter(const float* __restrict__ x, const int* __restrict__ rows,
                          const int* __restrict__ cols, const float* __restrict__ dinv,
                          float* __restrict__ out, int E) {
    long long t = (long long)blockIdx.x * blockDim.x + threadIdx.x;
    int e = (int)(t >> 6);
    if (e >= E) return;
    int f = (int)(t & 63);
    int r = rows[e];
    int c = cols[e];
    float w = dinv[r] * dinv[c];
    float v = w * x[((long long)r << 6) + f];
#if defined(__gfx950__) || defined(__gfx942__) || defined(__gfx90a__)
    unsafeAtomicAdd(&out[((long long)c << 6) + f], v);  // hw global_atomic_add_f32
#else
    atomicAdd(&out[((long long)c << 6) + f], v);
#endif
}

extern "C" void kernel_launch(void* const* d_in, const int* in_sizes, int n_in,
                              void* d_out, int out_size, void* d_ws, size_t ws_size,
                              hipStream_t stream) {
    const float* x    = (const float*)d_in[0];
    const int*   eidx = (const int*)d_in[1];   // int32: JAX x64 disabled

    const int n = in_sizes[0] / NFEAT;         // 100000
    const int E = in_sizes[1] / 2;             // 1600000
    const int* rows = eidx;                    // edge_index[0]
    const int* cols = eidx + E;                // edge_index[1]

    float* out = (float*)d_out;

    // workspace: deg (int, n) | dinv (float, n)
    int*   deg  = (int*)d_ws;
    float* dinv = (float*)((char*)d_ws + (size_t)n * sizeof(int));

    const int B = 256;

    k_init_deg<<<(n + B - 1) / B, B, 0, stream>>>(deg, n);
    k_count<<<(E + B - 1) / B, B, 0, stream>>>(rows, deg, E);
    k_dinv<<<(n + B - 1) / B, B, 0, stream>>>(deg, dinv, n);

    long long total = (long long)n * NFEAT;
    k_self<<<(int)((total + B - 1) / B), B, 0, stream>>>(x, dinv, out, total);

    long long st = (long long)E * NFEAT;
    k_scatter<<<(int)((st + B - 1) / B), B, 0, stream>>>(x, rows, cols, dinv, out, E);
}

// Round 2
// 429.175 us; speedup vs baseline: 1.1637x; 1.1637x over previous
//
#include <hip/hip_runtime.h>

#define NFEAT 64

// ---------------------------------------------------------------------------
// CSR-gather formulation (no fp32 atomics):
//   deg[i]   = 1 + #edges with row==i          (rows histogram, self loop)
//   dinv[i]  = rsqrt(deg[i])
//   CSR by col: ptr = exclusive_scan(hist(cols)); csr_rows[bucket] = row
//   out[c,f] = dinv[c]^2 * x[c,f] + dinv[c] * sum_{e in bucket c} dinv[r_e]*x[r_e,f]
// One wave per output node in the gather -> out written exactly once.
// ---------------------------------------------------------------------------

__global__ void k_init(int* __restrict__ deg, int* __restrict__ cnt, int n) {
    int i = blockIdx.x * blockDim.x + threadIdx.x;
    if (i < n) { deg[i] = 1; cnt[i] = 0; }
}

__global__ void k_hist(const int* __restrict__ rows, const int* __restrict__ cols,
                       int* __restrict__ deg, int* __restrict__ cnt, int E) {
    int e = blockIdx.x * blockDim.x + threadIdx.x;
    if (e < E) {
        atomicAdd(&deg[rows[e]], 1);
        atomicAdd(&cnt[cols[e]], 1);
    }
}

__global__ void k_dinv(const int* __restrict__ deg, float* __restrict__ dinv, int n) {
    int i = blockIdx.x * blockDim.x + threadIdx.x;
    if (i < n) dinv[i] = rsqrtf((float)deg[i]);
}

// --- 3-kernel exclusive scan of cnt -> ptr -------------------------------
__global__ void k_scan1(const int* __restrict__ cnt, int* __restrict__ ptr,
                        int* __restrict__ partials, int n) {
    __shared__ int sh[256];
    int t = threadIdx.x;
    int i = blockIdx.x * 256 + t;
    int v = (i < n) ? cnt[i] : 0;
    sh[t] = v;
    __syncthreads();
    for (int off = 1; off < 256; off <<= 1) {
        int add = (t >= off) ? sh[t - off] : 0;
        __syncthreads();
        sh[t] += add;
        __syncthreads();
    }
    int incl = sh[t];
    if (i < n) ptr[i] = incl - v;          // exclusive
    if (t == 255) partials[blockIdx.x] = incl;
}

__global__ void k_scan2(int* __restrict__ partials, int NB) {
    __shared__ int sh[512];
    int t = threadIdx.x;
    int v = (t < NB) ? partials[t] : 0;
    sh[t] = v;
    __syncthreads();
    for (int off = 1; off < 512; off <<= 1) {
        int add = (t >= off) ? sh[t - off] : 0;
        __syncthreads();
        sh[t] += add;
        __syncthreads();
    }
    if (t < NB) partials[t] = sh[t] - v;   // exclusive
}

__global__ void k_scan3(int* __restrict__ ptr, int* __restrict__ cur,
                        const int* __restrict__ partials, int n) {
    int i = blockIdx.x * 256 + threadIdx.x;
    if (i < n) {
        int val = ptr[i] + partials[blockIdx.x];
        ptr[i] = val;
        cur[i] = val;
    }
}

// --- fill CSR buckets (order within bucket arbitrary; fp32 reassoc ok) ----
__global__ void k_fill(const int* __restrict__ rows, const int* __restrict__ cols,
                       int* __restrict__ cur, int* __restrict__ csr_rows, int E) {
    int e = blockIdx.x * blockDim.x + threadIdx.x;
    if (e < E) {
        int c = cols[e];
        int p = atomicAdd(&cur[c], 1);
        csr_rows[p] = rows[e];
    }
}

// --- gather: one wave (64 lanes = 64 features) per output node ------------
__global__ void k_gather(const float* __restrict__ x, const float* __restrict__ dinv,
                         const int* __restrict__ ptr, const int* __restrict__ csr_rows,
                         float* __restrict__ out, int n, int E) {
    int node = blockIdx.x * 4 + (threadIdx.x >> 6);
    if (node >= n) return;
    int lane = threadIdx.x & 63;

    int start = ptr[node];
    int end   = (node + 1 < n) ? ptr[node + 1] : E;

    float acc = 0.0f;
    int j = start;
    for (; j + 1 < end; j += 2) {   // unroll-2 for load ILP
        int r0 = csr_rows[j];
        int r1 = csr_rows[j + 1];
        float w0 = dinv[r0];
        float w1 = dinv[r1];
        float x0 = x[((long long)r0 << 6) + lane];
        float x1 = x[((long long)r1 << 6) + lane];
        acc += w0 * x0 + w1 * x1;
    }
    if (j < end) {
        int r0 = csr_rows[j];
        acc += dinv[r0] * x[((long long)r0 << 6) + lane];
    }

    float dc = dinv[node];
    float self = dc * x[((long long)node << 6) + lane];  // dinv[c]^2 * x via dc*(dc*x)
    out[((long long)node << 6) + lane] = dc * (acc + self);
}

extern "C" void kernel_launch(void* const* d_in, const int* in_sizes, int n_in,
                              void* d_out, int out_size, void* d_ws, size_t ws_size,
                              hipStream_t stream) {
    const float* x    = (const float*)d_in[0];
    const int*   eidx = (const int*)d_in[1];   // int32 (JAX x64 disabled)

    const int n = in_sizes[0] / NFEAT;         // 100000
    const int E = in_sizes[1] / 2;             // 1600000
    const int* rows = eidx;
    const int* cols = eidx + E;

    float* out = (float*)d_out;

    // workspace layout (all 4-byte types)
    char* w = (char*)d_ws;
    int*   deg      = (int*)w;                 w += (size_t)n * 4;
    int*   cnt      = (int*)w;                 w += (size_t)n * 4;
    int*   ptr      = (int*)w;                 w += (size_t)n * 4;
    int*   cur      = (int*)w;                 w += (size_t)n * 4;
    float* dinv     = (float*)w;               w += (size_t)n * 4;
    int*   partials = (int*)w;                 w += 512 * 4;
    int*   csr_rows = (int*)w;                 /* E ints */

    const int B  = 256;
    const int NB = (n + B - 1) / B;            // 391 scan blocks (<= 512)

    k_init<<<(n + B - 1) / B, B, 0, stream>>>(deg, cnt, n);
    k_hist<<<(E + B - 1) / B, B, 0, stream>>>(rows, cols, deg, cnt, E);
    k_dinv<<<(n + B - 1) / B, B, 0, stream>>>(deg, dinv, n);

    k_scan1<<<NB, 256, 0, stream>>>(cnt, ptr, partials, n);
    k_scan2<<<1, 512, 0, stream>>>(partials, NB);
    k_scan3<<<NB, 256, 0, stream>>>(ptr, cur, partials, n);

    k_fill<<<(E + B - 1) / B, B, 0, stream>>>(rows, cols, cur, csr_rows, E);

    k_gather<<<(n + 3) / 4, 256, 0, stream>>>(x, dinv, ptr, csr_rows, out, n, E);
}

// Round 3
// 264.855 us; speedup vs baseline: 1.8857x; 1.6204x over previous
//
#include <hip/hip_runtime.h>

#define NFEAT 64
#define BSHIFT 8
#define BCOLS 256              // cols per bucket = 1<<BSHIFT
#define MAXNB 512              // >= nbuck = ceil(100000/256) = 391
#define CHUNK 4096             // edges per phase-A block
#define MAXB 6144              // phase-B LDS stage capacity (avg 4096, 32 sigma)

// ---------------------------------------------------------------------------
// out[c,f] = dinv[c]^2 x[c,f] + dinv[c] * sum_{e: col==c} dinv[row_e] x[row_e,f]
// dinv[i] = rsqrt(1 + #edges with row==i)
//
// CSR build via 2-phase LDS partition (no per-edge random global stores):
//   k_count_all : deg hist (global atomics) + per-bucket col counts (LDS hist)
//   k_bscan     : tiny scan of bucket counts -> bucket_start/cursor
//   k_part      : partition edges into col-buckets, packed (col_local<<17|row),
//                 LDS-staged so part[] writes are run-coalesced
//   k_fillB     : one block per bucket: per-col count+scan+slot in LDS,
//                 writes ptr[] and csr_rows[] fully coalesced
//   k_gather    : one wave per node, unroll-4, single write of out
// ---------------------------------------------------------------------------

__global__ void k_count_all(const int* __restrict__ rows, const int* __restrict__ cols,
                            int* __restrict__ deg, int* __restrict__ btot,
                            int E, int nbuck) {
    __shared__ int h[MAXNB];
    for (int i = threadIdx.x; i < nbuck; i += blockDim.x) h[i] = 0;
    __syncthreads();
    int stride = gridDim.x * blockDim.x;
    for (int e = blockIdx.x * blockDim.x + threadIdx.x; e < E; e += stride) {
        atomicAdd(&deg[rows[e]], 1);
        atomicAdd(&h[cols[e] >> BSHIFT], 1);
    }
    __syncthreads();
    for (int i = threadIdx.x; i < nbuck; i += blockDim.x)
        if (h[i]) atomicAdd(&btot[i], h[i]);
}

__global__ void k_bscan(const int* __restrict__ btot, int* __restrict__ bstart,
                        int* __restrict__ bcur, int* __restrict__ ptr,
                        int nbuck, int E, int n) {
    __shared__ int sh[512];
    int t = threadIdx.x;
    int v = (t < nbuck) ? btot[t] : 0;
    sh[t] = v;
    __syncthreads();
    for (int off = 1; off < 512; off <<= 1) {
        int a = (t >= off) ? sh[t - off] : 0;
        __syncthreads();
        sh[t] += a;
        __syncthreads();
    }
    if (t < nbuck) { int ex = sh[t] - v; bstart[t] = ex; bcur[t] = ex; }
    if (t == 0) { bstart[nbuck] = E; ptr[n] = E; }
}

__global__ void k_dinv(const int* __restrict__ deg, float* __restrict__ dinv, int n) {
    int i = blockIdx.x * blockDim.x + threadIdx.x;
    if (i < n) dinv[i] = rsqrtf((float)(deg[i] + 1));   // +1 = self loop
}

// Phase A: partition edges by col-bucket. Packed entry = (col&255)<<17 | row.
__global__ void k_part(const int* __restrict__ rows, const int* __restrict__ cols,
                       int* __restrict__ bcur, int* __restrict__ part,
                       int E, int nbuck) {
    __shared__ int hist[MAXNB];     // counts, then per-bucket cursor
    __shared__ int cbase[MAXNB];    // exclusive scan within chunk
    __shared__ int gbase[MAXNB];    // global offset - chunk-local start
    __shared__ int stage[CHUNK];
    __shared__ unsigned short bid[CHUNK];
    __shared__ int partials[256];

    int chunk0 = blockIdx.x * CHUNK;
    int cnt = min(CHUNK, E - chunk0);
    int t = threadIdx.x;

    for (int i = t; i < nbuck; i += 256) hist[i] = 0;
    __syncthreads();
    for (int i = t; i < cnt; i += 256)
        atomicAdd(&hist[cols[chunk0 + i] >> BSHIFT], 1);
    __syncthreads();

    // exclusive scan of hist -> cbase (256 threads x 2 slots)
    int i0 = 2 * t, i1 = 2 * t + 1;
    int a = (i0 < nbuck) ? hist[i0] : 0;
    int b = (i1 < nbuck) ? hist[i1] : 0;
    int loc = a + b;
    partials[t] = loc;
    __syncthreads();
    for (int off = 1; off < 256; off <<= 1) {
        int x = (t >= off) ? partials[t - off] : 0;
        __syncthreads();
        partials[t] += x;
        __syncthreads();
    }
    int base = partials[t] - loc;          // exclusive over pair-sums
    if (i0 < nbuck) cbase[i0] = base;
    if (i1 < nbuck) cbase[i1] = base + a;
    __syncthreads();

    // claim global space per bucket; set gbase = gpos - local_start; hist -> cursor
    for (int i = t; i < nbuck; i += 256) {
        int c_i = hist[i];
        int s   = cbase[i];
        if (c_i) gbase[i] = atomicAdd(&bcur[i], c_i) - s;
        hist[i] = s;
    }
    __syncthreads();

    // scatter into LDS stage ordered by bucket (re-read edges: L2-hot)
    for (int i = t; i < cnt; i += 256) {
        int c = cols[chunk0 + i];
        int r = rows[chunk0 + i];
        int bb = c >> BSHIFT;
        int p = atomicAdd(&hist[bb], 1);
        stage[p] = ((c & (BCOLS - 1)) << 17) | r;
        bid[p] = (unsigned short)bb;
    }
    __syncthreads();

    // write out: consecutive p within a bucket -> consecutive global -> coalesced runs
    for (int p = t; p < cnt; p += 256) {
        int bb = bid[p];
        part[gbase[bb] + p] = stage[p];
    }
}

// Phase B: one block per bucket. All counting/scanning/slotting in LDS.
__global__ void k_fillB(const int* __restrict__ part, const int* __restrict__ bstart,
                        int* __restrict__ ptr, int* __restrict__ csr, int n) {
    __shared__ int lcnt[BCOLS];
    __shared__ int lptr[BCOLS];
    __shared__ int cur[BCOLS];
    __shared__ int stage[MAXB];
    int b = blockIdx.x;
    int s = bstart[b], e = bstart[b + 1];
    int cnt = e - s;
    int col0 = b << BSHIFT;
    int t = threadIdx.x;    // blockDim == BCOLS == 256

    lcnt[t] = 0;
    __syncthreads();
    for (int i = t; i < cnt; i += 256)
        atomicAdd(&lcnt[part[s + i] >> 17], 1);
    __syncthreads();

    // exclusive scan of lcnt (256 elems, 256 threads)
    int v = lcnt[t];
    lptr[t] = v;
    __syncthreads();
    for (int off = 1; off < 256; off <<= 1) {
        int a = (t >= off) ? lptr[t - off] : 0;
        __syncthreads();
        lptr[t] += a;
        __syncthreads();
    }
    int ex = lptr[t] - v;
    cur[t] = ex;
    int c = col0 + t;
    if (c < n) ptr[c] = s + ex;
    __syncthreads();

    // slot + stage in LDS
    for (int i = t; i < cnt; i += 256) {
        int v2 = part[s + i];
        int cl = v2 >> 17;
        int r  = v2 & 0x1FFFF;
        int p = atomicAdd(&cur[cl], 1);
        if (p < MAXB) stage[p] = r;
        else csr[s + p] = r;   // statistically-impossible overflow fallback
    }
    __syncthreads();

    int lim = min(cnt, MAXB);
    for (int p = t; p < lim; p += 256) csr[s + p] = stage[p];  // coalesced
}

// gather: one wave (64 lanes = 64 features) per node, unroll-4 for MLP
__global__ void k_gather(const float* __restrict__ x, const float* __restrict__ dinv,
                         const int* __restrict__ ptr, const int* __restrict__ csr,
                         float* __restrict__ out, int n) {
    int node = blockIdx.x * 4 + (threadIdx.x >> 6);
    if (node >= n) return;
    int lane = threadIdx.x & 63;
    int s = ptr[node], e = ptr[node + 1];
    float acc0 = 0.f, acc1 = 0.f, acc2 = 0.f, acc3 = 0.f;
    int j = s;
    for (; j + 3 < e; j += 4) {
        int r0 = csr[j], r1 = csr[j + 1], r2 = csr[j + 2], r3 = csr[j + 3];
        float w0 = dinv[r0], w1 = dinv[r1], w2 = dinv[r2], w3 = dinv[r3];
        float x0 = x[((size_t)r0 << 6) + lane];
        float x1 = x[((size_t)r1 << 6) + lane];
        float x2 = x[((size_t)r2 << 6) + lane];
        float x3 = x[((size_t)r3 << 6) + lane];
        acc0 += w0 * x0; acc1 += w1 * x1; acc2 += w2 * x2; acc3 += w3 * x3;
    }
    for (; j < e; j++) {
        int r = csr[j];
        acc0 += dinv[r] * x[((size_t)r << 6) + lane];
    }
    float dc = dinv[node];
    float self = dc * x[((size_t)node << 6) + lane];
    out[((size_t)node << 6) + lane] = dc * (acc0 + acc1 + acc2 + acc3 + self);
}

extern "C" void kernel_launch(void* const* d_in, const int* in_sizes, int n_in,
                              void* d_out, int out_size, void* d_ws, size_t ws_size,
                              hipStream_t stream) {
    const float* x    = (const float*)d_in[0];
    const int*   eidx = (const int*)d_in[1];   // int32 (JAX x64 disabled)

    const int n = in_sizes[0] / NFEAT;         // 100000
    const int E = in_sizes[1] / 2;             // 1600000
    const int* rows = eidx;
    const int* cols = eidx + E;
    float* out = (float*)d_out;

    const int nbuck = (n + BCOLS - 1) >> BSHIFT;   // 391

    // ws layout: deg[n] | btot[MAXNB]  (contiguous: one memset) | bstart[MAXNB+1]
    //            | bcur[MAXNB] | ptr[n+1] | dinv[n] | part[E] | csr[E]
    char* w = (char*)d_ws;
    int*   deg    = (int*)w;          w += (size_t)n * 4;
    int*   btot   = (int*)w;          w += (size_t)MAXNB * 4;
    int*   bstart = (int*)w;          w += (size_t)(MAXNB + 1) * 4;
    int*   bcur   = (int*)w;          w += (size_t)MAXNB * 4;
    int*   ptr    = (int*)w;          w += (size_t)(n + 1) * 4;
    float* dinv   = (float*)w;        w += (size_t)n * 4;
    int*   part   = (int*)w;          w += (size_t)E * 4;
    int*   csr    = (int*)w;

    hipMemsetAsync(deg, 0, ((size_t)n + MAXNB) * 4, stream);

    k_count_all<<<512, 256, 0, stream>>>(rows, cols, deg, btot, E, nbuck);
    k_bscan<<<1, 512, 0, stream>>>(btot, bstart, bcur, ptr, nbuck, E, n);
    k_dinv<<<(n + 255) / 256, 256, 0, stream>>>(deg, dinv, n);

    int nchunk = (E + CHUNK - 1) / CHUNK;
    k_part<<<nchunk, 256, 0, stream>>>(rows, cols, bcur, part, E, nbuck);
    k_fillB<<<nbuck, 256, 0, stream>>>(part, bstart, ptr, csr, n);

    k_gather<<<(n + 3) / 4, 256, 0, stream>>>(x, dinv, ptr, csr, out, n);
}

// Round 4
// 219.016 us; speedup vs baseline: 2.2804x; 1.2093x over previous
//
#include <hip/hip_runtime.h>

#define NFEAT 64
#define BSHIFT 9
#define BCOLS 512              // cols/rows per bucket = 1<<BSHIFT
#define NB2 256                // max buckets (nbuck = ceil(100000/512) = 196)
#define CHUNK 4096             // edges per partition block
#define MAXB 10240             // phase-B LDS stage capacity (avg 8192, >20 sigma)

// ---------------------------------------------------------------------------
// out[c,f] = dinv[c]^2 x[c,f] + dinv[c] * sum_{e: col==c} dinv[row_e] x[row_e,f]
// dinv[i] = rsqrt(1 + #edges with row==i)
//
// No per-edge random global atomics anywhere:
//   k_hist2  : LDS bucket histograms of cols and rows (btot/btotR)
//   k_bscan2 : scans -> bucket starts/cursors
//   k_part   : partition edges by col-bucket, packed (col_local<<17|row)
//   k_partR  : partition row ids by row-bucket (aliases csr storage)
//   k_fillR  : per-bucket LDS row counts -> dinv written coalesced
//   k_fillB  : per-bucket LDS col counts/scan/slot -> ptr + csr coalesced
//   k_gather : wave per node; csr+dinv batch-loaded, shfl-broadcast, unroll-8
// ---------------------------------------------------------------------------

__global__ void k_hist2(const int* __restrict__ rows, const int* __restrict__ cols,
                        int* __restrict__ btot, int* __restrict__ btotR,
                        int E, int nbuck) {
    __shared__ int hC[NB2];
    __shared__ int hR[NB2];
    int t = threadIdx.x;
    hC[t] = 0; hR[t] = 0;
    __syncthreads();
    int stride = gridDim.x * blockDim.x;
    for (int e = blockIdx.x * blockDim.x + t; e < E; e += stride) {
        atomicAdd(&hC[cols[e] >> BSHIFT], 1);
        atomicAdd(&hR[rows[e] >> BSHIFT], 1);
    }
    __syncthreads();
    if (t < nbuck) {
        if (hC[t]) atomicAdd(&btot[t], hC[t]);
        if (hR[t]) atomicAdd(&btotR[t], hR[t]);
    }
}

__global__ void k_bscan2(const int* __restrict__ btot, const int* __restrict__ btotR,
                         int* __restrict__ bstart, int* __restrict__ bcur,
                         int* __restrict__ bstartR, int* __restrict__ bcurR,
                         int* __restrict__ ptr, int nbuck, int E, int n) {
    __shared__ int sh[NB2];
    int t = threadIdx.x;
    int v = (t < nbuck) ? btot[t] : 0;
    sh[t] = v; __syncthreads();
    for (int off = 1; off < NB2; off <<= 1) {
        int a = (t >= off) ? sh[t - off] : 0; __syncthreads();
        sh[t] += a; __syncthreads();
    }
    if (t < nbuck) { int ex = sh[t] - v; bstart[t] = ex; bcur[t] = ex; }
    if (t == 0) { bstart[nbuck] = E; ptr[n] = E; }
    __syncthreads();
    int v2 = (t < nbuck) ? btotR[t] : 0;
    sh[t] = v2; __syncthreads();
    for (int off = 1; off < NB2; off <<= 1) {
        int a = (t >= off) ? sh[t - off] : 0; __syncthreads();
        sh[t] += a; __syncthreads();
    }
    if (t < nbuck) { int ex = sh[t] - v2; bstartR[t] = ex; bcurR[t] = ex; }
    if (t == 0) bstartR[nbuck] = E;
}

// partition by col-bucket; entry = (col&511)<<17 | row  (row < 2^17)
__global__ void k_part(const int* __restrict__ rows, const int* __restrict__ cols,
                       int* __restrict__ bcur, int* __restrict__ part, int E) {
    __shared__ int hist[NB2];       // counts -> cursor
    __shared__ int scan[NB2];
    __shared__ int gbase[NB2];
    __shared__ int stage[CHUNK];
    __shared__ unsigned char bid[CHUNK];
    int chunk0 = blockIdx.x * CHUNK;
    int cnt = min(CHUNK, E - chunk0);
    int t = threadIdx.x;            // 256 == NB2
    hist[t] = 0;
    __syncthreads();
    for (int i = t; i < cnt; i += 256)
        atomicAdd(&hist[cols[chunk0 + i] >> BSHIFT], 1);
    __syncthreads();
    int v = hist[t];
    scan[t] = v; __syncthreads();
    for (int off = 1; off < NB2; off <<= 1) {
        int a = (t >= off) ? scan[t - off] : 0; __syncthreads();
        scan[t] += a; __syncthreads();
    }
    int ex = scan[t] - v;           // chunk-local start of bucket t
    if (v > 0) gbase[t] = atomicAdd(&bcur[t], v) - ex;
    hist[t] = ex;                   // becomes cursor
    __syncthreads();
    for (int i = t; i < cnt; i += 256) {
        int c = cols[chunk0 + i];
        int r = rows[chunk0 + i];
        int bb = c >> BSHIFT;
        int p = atomicAdd(&hist[bb], 1);
        stage[p] = ((c & (BCOLS - 1)) << 17) | r;
        bid[p] = (unsigned char)bb;
    }
    __syncthreads();
    for (int p = t; p < cnt; p += 256)   // consecutive within bucket -> coalesced runs
        part[gbase[bid[p]] + p] = stage[p];
}

// partition row ids by row-bucket (for degree counting)
__global__ void k_partR(const int* __restrict__ rows,
                        int* __restrict__ bcurR, int* __restrict__ partR, int E) {
    __shared__ int hist[NB2];
    __shared__ int scan[NB2];
    __shared__ int gbase[NB2];
    __shared__ int stage[CHUNK];
    __shared__ unsigned char bid[CHUNK];
    int chunk0 = blockIdx.x * CHUNK;
    int cnt = min(CHUNK, E - chunk0);
    int t = threadIdx.x;
    hist[t] = 0;
    __syncthreads();
    for (int i = t; i < cnt; i += 256)
        atomicAdd(&hist[rows[chunk0 + i] >> BSHIFT], 1);
    __syncthreads();
    int v = hist[t];
    scan[t] = v; __syncthreads();
    for (int off = 1; off < NB2; off <<= 1) {
        int a = (t >= off) ? scan[t - off] : 0; __syncthreads();
        scan[t] += a; __syncthreads();
    }
    int ex = scan[t] - v;
    if (v > 0) gbase[t] = atomicAdd(&bcurR[t], v) - ex;
    hist[t] = ex;
    __syncthreads();
    for (int i = t; i < cnt; i += 256) {
        int r = rows[chunk0 + i];
        int bb = r >> BSHIFT;
        int p = atomicAdd(&hist[bb], 1);
        stage[p] = r;
        bid[p] = (unsigned char)bb;
    }
    __syncthreads();
    for (int p = t; p < cnt; p += 256)
        partR[gbase[bid[p]] + p] = stage[p];
}

// per-bucket row counts in LDS -> dinv (coalesced write)
__global__ void k_fillR(const int* __restrict__ partR, const int* __restrict__ bstartR,
                        float* __restrict__ dinv, int n) {
    __shared__ int lcnt[BCOLS];
    int b = blockIdx.x;
    int s = bstartR[b], e = bstartR[b + 1];
    int t = threadIdx.x;            // 512
    lcnt[t] = 0;
    __syncthreads();
    for (int i = s + t; i < e; i += 512)
        atomicAdd(&lcnt[partR[i] & (BCOLS - 1)], 1);
    __syncthreads();
    int r = (b << BSHIFT) + t;
    if (r < n) dinv[r] = rsqrtf((float)(lcnt[t] + 1));   // +1 self loop
}

// per-bucket col counts/scan/slot in LDS -> ptr + csr (coalesced)
__global__ void k_fillB(const int* __restrict__ part, const int* __restrict__ bstart,
                        int* __restrict__ ptr, int* __restrict__ csr, int n) {
    __shared__ int lcnt[BCOLS];
    __shared__ int lptr[BCOLS];
    __shared__ int cur[BCOLS];
    __shared__ int stage[MAXB];
    int b = blockIdx.x;
    int s = bstart[b], e = bstart[b + 1];
    int cnt = e - s;
    int t = threadIdx.x;            // 512 == BCOLS
    lcnt[t] = 0;
    __syncthreads();
    for (int i = t; i < cnt; i += 512)
        atomicAdd(&lcnt[part[s + i] >> 17], 1);
    __syncthreads();
    int v = lcnt[t];
    lptr[t] = v; __syncthreads();
    for (int off = 1; off < BCOLS; off <<= 1) {
        int a = (t >= off) ? lptr[t - off] : 0; __syncthreads();
        lptr[t] += a; __syncthreads();
    }
    int ex = lptr[t] - v;
    cur[t] = ex;
    int c = (b << BSHIFT) + t;
    if (c < n) ptr[c] = s + ex;
    __syncthreads();
    for (int i = t; i < cnt; i += 512) {
        int v2 = part[s + i];
        int cl = v2 >> 17;
        int r  = v2 & 0x1FFFF;
        int p = atomicAdd(&cur[cl], 1);
        if (p < MAXB) stage[p] = r;
        else csr[s + p] = r;        // statistically-impossible overflow fallback
    }
    __syncthreads();
    int lim = min(cnt, MAXB);
    for (int p = t; p < lim; p += 512) csr[s + p] = stage[p];
}

// wave per node: batch-load 64 (r,w) pairs, shfl-broadcast, unroll-8 x stream
__global__ void k_gather(const float* __restrict__ x, const float* __restrict__ dinv,
                         const int* __restrict__ ptr, const int* __restrict__ csr,
                         float* __restrict__ out, int n) {
    int node = blockIdx.x * 4 + (threadIdx.x >> 6);
    if (node >= n) return;
    int lane = threadIdx.x & 63;
    int s = ptr[node], e = ptr[node + 1];
    float a0 = 0.f, a1 = 0.f, a2 = 0.f, a3 = 0.f;
    for (int base = s; base < e; base += 64) {
        int m = e - base; if (m > 64) m = 64;
        int idx = base + ((lane < m) ? lane : (m - 1));  // clamp: dup loads broadcast
        int   myr = csr[idx];
        float myw = dinv[myr];
        int j = 0;
        for (; j + 8 <= m; j += 8) {
            int r0 = __shfl(myr, j),     r1 = __shfl(myr, j + 1);
            int r2 = __shfl(myr, j + 2), r3 = __shfl(myr, j + 3);
            int r4 = __shfl(myr, j + 4), r5 = __shfl(myr, j + 5);
            int r6 = __shfl(myr, j + 6), r7 = __shfl(myr, j + 7);
            float w0 = __shfl(myw, j),     w1 = __shfl(myw, j + 1);
            float w2 = __shfl(myw, j + 2), w3 = __shfl(myw, j + 3);
            float w4 = __shfl(myw, j + 4), w5 = __shfl(myw, j + 5);
            float w6 = __shfl(myw, j + 6), w7 = __shfl(myw, j + 7);
            a0 += w0 * x[((size_t)r0 << 6) + lane];
            a1 += w1 * x[((size_t)r1 << 6) + lane];
            a2 += w2 * x[((size_t)r2 << 6) + lane];
            a3 += w3 * x[((size_t)r3 << 6) + lane];
            a0 += w4 * x[((size_t)r4 << 6) + lane];
            a1 += w5 * x[((size_t)r5 << 6) + lane];
            a2 += w6 * x[((size_t)r6 << 6) + lane];
            a3 += w7 * x[((size_t)r7 << 6) + lane];
        }
        for (; j < m; j++) {
            int r0 = __shfl(myr, j);
            float w0 = __shfl(myw, j);
            a0 += w0 * x[((size_t)r0 << 6) + lane];
        }
    }
    float dc = dinv[node];
    float acc = (a0 + a1) + (a2 + a3) + dc * x[((size_t)node << 6) + lane];
    out[((size_t)node << 6) + lane] = dc * acc;
}

extern "C" void kernel_launch(void* const* d_in, const int* in_sizes, int n_in,
                              void* d_out, int out_size, void* d_ws, size_t ws_size,
                              hipStream_t stream) {
    const float* x    = (const float*)d_in[0];
    const int*   eidx = (const int*)d_in[1];   // int32 (JAX x64 disabled)

    const int n = in_sizes[0] / NFEAT;         // 100000
    const int E = in_sizes[1] / 2;             // 1600000
    const int* rows = eidx;
    const int* cols = eidx + E;
    float* out = (float*)d_out;

    const int nbuck = (n + BCOLS - 1) >> BSHIFT;   // 196

    // ws: btot[NB2]|btotR[NB2] (memset together) | bstart[NB2+1]|bstartR[NB2+1]
    //     |bcur[NB2]|bcurR[NB2] | ptr[n+1] | dinv[n] | part[E] | csr[E] (aliases partR)
    char* w = (char*)d_ws;
    int*   btot    = (int*)w;   w += NB2 * 4;
    int*   btotR   = (int*)w;   w += NB2 * 4;
    int*   bstart  = (int*)w;   w += (NB2 + 1) * 4;
    int*   bstartR = (int*)w;   w += (NB2 + 1) * 4;
    int*   bcur    = (int*)w;   w += NB2 * 4;
    int*   bcurR   = (int*)w;   w += NB2 * 4;
    int*   ptr     = (int*)w;   w += (size_t)(n + 1) * 4;
    float* dinv    = (float*)w; w += (size_t)n * 4;
    int*   part    = (int*)w;   w += (size_t)E * 4;
    int*   csr     = (int*)w;   // E ints; partR aliases this (dead before fillB)
    int*   partR   = csr;

    hipMemsetAsync(btot, 0, 2 * NB2 * 4, stream);

    k_hist2<<<256, 256, 0, stream>>>(rows, cols, btot, btotR, E, nbuck);
    k_bscan2<<<1, NB2, 0, stream>>>(btot, btotR, bstart, bcur, bstartR, bcurR,
                                    ptr, nbuck, E, n);

    int nchunk = (E + CHUNK - 1) / CHUNK;
    k_partR<<<nchunk, 256, 0, stream>>>(rows, bcurR, partR, E);
    k_fillR<<<nbuck, BCOLS, 0, stream>>>(partR, bstartR, dinv, n);

    k_part<<<nchunk, 256, 0, stream>>>(rows, cols, bcur, part, E);
    k_fillB<<<nbuck, BCOLS, 0, stream>>>(part, bstart, ptr, csr, n);

    k_gather<<<(n + 3) / 4, 256, 0, stream>>>(x, dinv, ptr, csr, out, n);
}

// Round 5
// 206.028 us; speedup vs baseline: 2.4241x; 1.0630x over previous
//
#include <hip/hip_runtime.h>

#define NFEAT 64
#define BSHIFT 9
#define BCOLS 512              // cols/rows per bucket = 1<<BSHIFT
#define NB2 256                // max buckets (nbuck = ceil(100000/512) = 196)
#define CHUNK 8192             // edges per partition block (runs ~42*4B=168B)
#define PTHREADS 512           // partition block size
#define MAXB 10240             // phase-B LDS stage capacity (avg 8192, >20 sigma)

// ---------------------------------------------------------------------------
// out[c,f] = dinv[c]^2 x[c,f] + dinv[c] * sum_{e: col==c} dinv[row_e] x[row_e,f]
// dinv[i] = rsqrt(1 + #edges with row==i)
//
// No per-edge random global atomics anywhere:
//   k_hist2  : LDS bucket histograms of cols and rows (btot/btotR)
//   k_bscan2 : scans -> bucket starts/cursors
//   k_part   : partition edges by col-bucket, packed (col_local<<17|row)
//   k_partR  : partition row ids by row-bucket (aliases csr storage)
//   k_fillR  : per-bucket LDS row counts -> dinv written coalesced
//   k_fillB  : per-bucket LDS col counts/scan/slot -> ptr + csr coalesced
//   k_gather : wave per node; float4 lanes, 4 edges per load instruction
// ---------------------------------------------------------------------------

__global__ void k_hist2(const int* __restrict__ rows, const int* __restrict__ cols,
                        int* __restrict__ btot, int* __restrict__ btotR,
                        int E, int nbuck) {
    __shared__ int hC[NB2];
    __shared__ int hR[NB2];
    int t = threadIdx.x;
    hC[t] = 0; hR[t] = 0;
    __syncthreads();
    int stride = gridDim.x * blockDim.x;
    for (int e = blockIdx.x * blockDim.x + t; e < E; e += stride) {
        atomicAdd(&hC[cols[e] >> BSHIFT], 1);
        atomicAdd(&hR[rows[e] >> BSHIFT], 1);
    }
    __syncthreads();
    if (t < nbuck) {
        if (hC[t]) atomicAdd(&btot[t], hC[t]);
        if (hR[t]) atomicAdd(&btotR[t], hR[t]);
    }
}

__global__ void k_bscan2(const int* __restrict__ btot, const int* __restrict__ btotR,
                         int* __restrict__ bstart, int* __restrict__ bcur,
                         int* __restrict__ bstartR, int* __restrict__ bcurR,
                         int* __restrict__ ptr, int nbuck, int E, int n) {
    __shared__ int sh[NB2];
    int t = threadIdx.x;
    int v = (t < nbuck) ? btot[t] : 0;
    sh[t] = v; __syncthreads();
    for (int off = 1; off < NB2; off <<= 1) {
        int a = (t >= off) ? sh[t - off] : 0; __syncthreads();
        sh[t] += a; __syncthreads();
    }
    if (t < nbuck) { int ex = sh[t] - v; bstart[t] = ex; bcur[t] = ex; }
    if (t == 0) { bstart[nbuck] = E; ptr[n] = E; }
    __syncthreads();
    int v2 = (t < nbuck) ? btotR[t] : 0;
    sh[t] = v2; __syncthreads();
    for (int off = 1; off < NB2; off <<= 1) {
        int a = (t >= off) ? sh[t - off] : 0; __syncthreads();
        sh[t] += a; __syncthreads();
    }
    if (t < nbuck) { int ex = sh[t] - v2; bstartR[t] = ex; bcurR[t] = ex; }
    if (t == 0) bstartR[nbuck] = E;
}

// partition by col-bucket; entry = (col&511)<<17 | row  (row < 2^17)
__global__ void k_part(const int* __restrict__ rows, const int* __restrict__ cols,
                       int* __restrict__ bcur, int* __restrict__ part, int E) {
    __shared__ int hist[NB2];       // counts -> cursor
    __shared__ int scan[NB2];
    __shared__ int gbase[NB2];
    __shared__ int stage[CHUNK];
    __shared__ unsigned char bid[CHUNK];
    int chunk0 = blockIdx.x * CHUNK;
    int cnt = min(CHUNK, E - chunk0);
    int t = threadIdx.x;            // PTHREADS
    if (t < NB2) hist[t] = 0;
    __syncthreads();
    for (int i = t; i < cnt; i += PTHREADS)
        atomicAdd(&hist[cols[chunk0 + i] >> BSHIFT], 1);
    __syncthreads();
    int v = 0;
    if (t < NB2) { v = hist[t]; scan[t] = v; }
    __syncthreads();
    for (int off = 1; off < NB2; off <<= 1) {
        int a = (t >= off && t < NB2) ? scan[t - off] : 0;
        __syncthreads();
        if (t < NB2) scan[t] += a;
        __syncthreads();
    }
    if (t < NB2) {
        int ex = scan[t] - v;       // chunk-local start of bucket t
        if (v > 0) gbase[t] = atomicAdd(&bcur[t], v) - ex;
        hist[t] = ex;               // becomes cursor
    }
    __syncthreads();
    for (int i = t; i < cnt; i += PTHREADS) {
        int c = cols[chunk0 + i];
        int r = rows[chunk0 + i];
        int bb = c >> BSHIFT;
        int p = atomicAdd(&hist[bb], 1);
        stage[p] = ((c & (BCOLS - 1)) << 17) | r;
        bid[p] = (unsigned char)bb;
    }
    __syncthreads();
    for (int p = t; p < cnt; p += PTHREADS)   // consecutive within bucket -> coalesced runs
        part[gbase[bid[p]] + p] = stage[p];
}

// partition row ids by row-bucket (for degree counting)
__global__ void k_partR(const int* __restrict__ rows,
                        int* __restrict__ bcurR, int* __restrict__ partR, int E) {
    __shared__ int hist[NB2];
    __shared__ int scan[NB2];
    __shared__ int gbase[NB2];
    __shared__ int stage[CHUNK];
    __shared__ unsigned char bid[CHUNK];
    int chunk0 = blockIdx.x * CHUNK;
    int cnt = min(CHUNK, E - chunk0);
    int t = threadIdx.x;
    if (t < NB2) hist[t] = 0;
    __syncthreads();
    for (int i = t; i < cnt; i += PTHREADS)
        atomicAdd(&hist[rows[chunk0 + i] >> BSHIFT], 1);
    __syncthreads();
    int v = 0;
    if (t < NB2) { v = hist[t]; scan[t] = v; }
    __syncthreads();
    for (int off = 1; off < NB2; off <<= 1) {
        int a = (t >= off && t < NB2) ? scan[t - off] : 0;
        __syncthreads();
        if (t < NB2) scan[t] += a;
        __syncthreads();
    }
    if (t < NB2) {
        int ex = scan[t] - v;
        if (v > 0) gbase[t] = atomicAdd(&bcurR[t], v) - ex;
        hist[t] = ex;
    }
    __syncthreads();
    for (int i = t; i < cnt; i += PTHREADS) {
        int r = rows[chunk0 + i];
        int bb = r >> BSHIFT;
        int p = atomicAdd(&hist[bb], 1);
        stage[p] = r;
        bid[p] = (unsigned char)bb;
    }
    __syncthreads();
    for (int p = t; p < cnt; p += PTHREADS)
        partR[gbase[bid[p]] + p] = stage[p];
}

// per-bucket row counts in LDS -> dinv (coalesced write)
__global__ void k_fillR(const int* __restrict__ partR, const int* __restrict__ bstartR,
                        float* __restrict__ dinv, int n) {
    __shared__ int lcnt[BCOLS];
    int b = blockIdx.x;
    int s = bstartR[b], e = bstartR[b + 1];
    int t = threadIdx.x;            // 512
    lcnt[t] = 0;
    __syncthreads();
    for (int i = s + t; i < e; i += 512)
        atomicAdd(&lcnt[partR[i] & (BCOLS - 1)], 1);
    __syncthreads();
    int r = (b << BSHIFT) + t;
    if (r < n) dinv[r] = rsqrtf((float)(lcnt[t] + 1));   // +1 self loop
}

// per-bucket col counts/scan/slot in LDS -> ptr + csr (coalesced)
__global__ void k_fillB(const int* __restrict__ part, const int* __restrict__ bstart,
                        int* __restrict__ ptr, int* __restrict__ csr, int n) {
    __shared__ int lcnt[BCOLS];
    __shared__ int lptr[BCOLS];
    __shared__ int cur[BCOLS];
    __shared__ int stage[MAXB];
    int b = blockIdx.x;
    int s = bstart[b], e = bstart[b + 1];
    int cnt = e - s;
    int t = threadIdx.x;            // 512 == BCOLS
    lcnt[t] = 0;
    __syncthreads();
    for (int i = t; i < cnt; i += 512)
        atomicAdd(&lcnt[part[s + i] >> 17], 1);
    __syncthreads();
    int v = lcnt[t];
    lptr[t] = v; __syncthreads();
    for (int off = 1; off < BCOLS; off <<= 1) {
        int a = (t >= off) ? lptr[t - off] : 0; __syncthreads();
        lptr[t] += a; __syncthreads();
    }
    int ex = lptr[t] - v;
    cur[t] = ex;
    int c = (b << BSHIFT) + t;
    if (c < n) ptr[c] = s + ex;
    __syncthreads();
    for (int i = t; i < cnt; i += 512) {
        int v2 = part[s + i];
        int cl = v2 >> 17;
        int r  = v2 & 0x1FFFF;
        int p = atomicAdd(&cur[cl], 1);
        if (p < MAXB) stage[p] = r;
        else csr[s + p] = r;        // statistically-impossible overflow fallback
    }
    __syncthreads();
    int lim = min(cnt, MAXB);
    for (int p = t; p < lim; p += 512) csr[s + p] = stage[p];
}

// wave per node: lane = (edge group g = lane>>4, feature quad li = lane&15).
// One float4 load instruction covers 4 edges (1 KiB/wave). Cross-group
// reduction via 2 shfl_xor at the end; out written once as float4 by 16 lanes.
__global__ void k_gather(const float4* __restrict__ x4, const float* __restrict__ dinv,
                         const int* __restrict__ ptr, const int* __restrict__ csr,
                         float4* __restrict__ out4, int n) {
    int node = blockIdx.x * 4 + (threadIdx.x >> 6);
    if (node >= n) return;
    int lane = threadIdx.x & 63;
    int g  = lane >> 4;
    int li = lane & 15;
    int s = ptr[node], e = ptr[node + 1];
    float4 a0 = make_float4(0.f, 0.f, 0.f, 0.f);
    float4 a1 = make_float4(0.f, 0.f, 0.f, 0.f);
    for (int base = s; base < e; base += 64) {
        int m = e - base; if (m > 64) m = 64;
        int idx = base + ((lane < m) ? lane : (m - 1));  // clamp: dup loads broadcast
        int   myr = csr[idx];
        float myw = (lane < m) ? dinv[myr] : 0.f;        // OOR edges weight 0
        int mr = (m + 7) & ~7;                           // <= 64
        for (int j = 0; j < mr; j += 8) {
            int   r0 = __shfl(myr, j + g);
            float w0 = __shfl(myw, j + g);
            int   r1 = __shfl(myr, j + 4 + g);
            float w1 = __shfl(myw, j + 4 + g);
            float4 v0 = x4[((size_t)r0 << 4) + li];
            float4 v1 = x4[((size_t)r1 << 4) + li];
            a0.x += w0 * v0.x; a0.y += w0 * v0.y; a0.z += w0 * v0.z; a0.w += w0 * v0.w;
            a1.x += w1 * v1.x; a1.y += w1 * v1.y; a1.z += w1 * v1.z; a1.w += w1 * v1.w;
        }
    }
    float4 a;
    a.x = a0.x + a1.x; a.y = a0.y + a1.y; a.z = a0.z + a1.z; a.w = a0.w + a1.w;
    a.x += __shfl_xor(a.x, 16); a.y += __shfl_xor(a.y, 16);
    a.z += __shfl_xor(a.z, 16); a.w += __shfl_xor(a.w, 16);
    a.x += __shfl_xor(a.x, 32); a.y += __shfl_xor(a.y, 32);
    a.z += __shfl_xor(a.z, 32); a.w += __shfl_xor(a.w, 32);
    if (lane < 16) {
        float dc = dinv[node];
        float4 xs = x4[((size_t)node << 4) + li];
        float4 r;
        r.x = dc * (a.x + dc * xs.x);
        r.y = dc * (a.y + dc * xs.y);
        r.z = dc * (a.z + dc * xs.z);
        r.w = dc * (a.w + dc * xs.w);
        out4[((size_t)node << 4) + li] = r;
    }
}

extern "C" void kernel_launch(void* const* d_in, const int* in_sizes, int n_in,
                              void* d_out, int out_size, void* d_ws, size_t ws_size,
                              hipStream_t stream) {
    const float* x    = (const float*)d_in[0];
    const int*   eidx = (const int*)d_in[1];   // int32 (JAX x64 disabled)

    const int n = in_sizes[0] / NFEAT;         // 100000
    const int E = in_sizes[1] / 2;             // 1600000
    const int* rows = eidx;
    const int* cols = eidx + E;
    float* out = (float*)d_out;

    const int nbuck = (n + BCOLS - 1) >> BSHIFT;   // 196

    // ws: btot[NB2]|btotR[NB2] (memset together) | bstart[NB2+1]|bstartR[NB2+1]
    //     |bcur[NB2]|bcurR[NB2] | ptr[n+1] | dinv[n] | part[E] | csr[E] (aliases partR)
    char* w = (char*)d_ws;
    int*   btot    = (int*)w;   w += NB2 * 4;
    int*   btotR   = (int*)w;   w += NB2 * 4;
    int*   bstart  = (int*)w;   w += (NB2 + 1) * 4;
    int*   bstartR = (int*)w;   w += (NB2 + 1) * 4;
    int*   bcur    = (int*)w;   w += NB2 * 4;
    int*   bcurR   = (int*)w;   w += NB2 * 4;
    int*   ptr     = (int*)w;   w += (size_t)(n + 1) * 4;
    float* dinv    = (float*)w; w += (size_t)n * 4;
    int*   part    = (int*)w;   w += (size_t)E * 4;
    int*   csr     = (int*)w;   // E ints; partR aliases this (dead before fillB)
    int*   partR   = csr;

    hipMemsetAsync(btot, 0, 2 * NB2 * 4, stream);

    k_hist2<<<256, 256, 0, stream>>>(rows, cols, btot, btotR, E, nbuck);
    k_bscan2<<<1, NB2, 0, stream>>>(btot, btotR, bstart, bcur, bstartR, bcurR,
                                    ptr, nbuck, E, n);

    int nchunk = (E + CHUNK - 1) / CHUNK;
    k_partR<<<nchunk, PTHREADS, 0, stream>>>(rows, bcurR, partR, E);
    k_fillR<<<nbuck, BCOLS, 0, stream>>>(partR, bstartR, dinv, n);

    k_part<<<nchunk, PTHREADS, 0, stream>>>(rows, cols, bcur, part, E);
    k_fillB<<<nbuck, BCOLS, 0, stream>>>(part, bstart, ptr, csr, n);

    k_gather<<<(n + 3) / 4, 256, 0, stream>>>((const float4*)x, dinv, ptr, csr,
                                              (float4*)out, n);
}